// Round 14
// baseline (220.882 us; speedup 1.0000x reference)
//
#include <hip/hip_runtime.h>
#include <hip/hip_bf16.h>

#define T_TOK 8193
#define MROWS 16386        // B*T
#define NBLK  64
#define GCH   16           // global-attn chunks per (b,h)
#define GCS   513          // chunk size (16*513 >= 8193)

typedef __attribute__((ext_vector_type(8))) short bf16x8;
typedef __attribute__((ext_vector_type(4))) float f32x4;
typedef unsigned short u16;
typedef unsigned int   u32;

__device__ __forceinline__ float blo(u32 u){ return __uint_as_float(u << 16); }
__device__ __forceinline__ float bhi(u32 u){ return __uint_as_float(u & 0xffff0000u); }
__device__ __forceinline__ u16 f2b(float f){
  u32 u = __float_as_uint(f);
  u = (u + 0x7fffu + ((u >> 16) & 1u)) >> 16;
  return (u16)u;
}
__device__ __forceinline__ float b2f(u16 v){ return __uint_as_float(((u32)v) << 16); }
__device__ __forceinline__ u32 cvtpk(float lo, float hi){
  u32 r; asm("v_cvt_pk_bf16_f32 %0, %1, %2" : "=v"(r) : "v"(lo), "v"(hi)); return r;
}

#define GLDS16(gsrc, ldst) \
  __builtin_amdgcn_global_load_lds((const __attribute__((address_space(1))) void*)(gsrc), \
                                   (__attribute__((address_space(3))) void*)(ldst), 16, 0, 0)

// ---------------- W [K][N] fp32 (up to 3 parts) -> W^T [N][K] bf16 ----------------
__global__ __launch_bounds__(256)
void transposeW(const float* __restrict__ B0, const float* __restrict__ B1,
                const float* __restrict__ B2, int bpart,
                u16* __restrict__ outT, int K)
{
  __shared__ float tile[64][65];
  const int n0 = blockIdx.x * 64;
  const int k0 = blockIdx.y * 64;
  const int tx = threadIdx.x & 63;
  const int ty = threadIdx.x >> 6;
  const int part = n0 / bpart;
  const float* Bm = part == 0 ? B0 : (part == 1 ? B1 : B2);
  const int bn = n0 - part * bpart;
  #pragma unroll
  for (int i = 0; i < 16; ++i) {
    int k = i * 4 + ty;
    tile[tx][k] = Bm[(size_t)(k0 + k) * bpart + bn + tx];
  }
  __syncthreads();
  #pragma unroll
  for (int i = 0; i < 16; ++i) {
    int r = i * 4 + ty;
    outT[(size_t)(n0 + r) * K + k0 + tx] = f2b(tile[r][tx]);
  }
}

// ---------------- gemmf: C_bf16 = bf16(X_f32[M x K]) * BT[N x K]^T ----------------
// 128x128 tile, BK=32, 2 LDS buffers, fused fp32->bf16 at frag-read.
// A staged fp32 via global_load_lds (4 loads/thread/buf); swizzle c^=(row&7)
// over 8 fp32-chunks/row -> frag reads are 2-way (free). Convert with
// v_cvt_pk_bf16_f32 (RNE, matches f2b): 4 instr per A-frag. B path identical
// to the verified r9/r13 kernels. Depth-1 pipeline (r13-validated): stage
// tile t+1 at P0 of t, vmcnt(0) at end of tile = full-tile latency cover.
__global__ __launch_bounds__(256, 4)
void gemmf(const float* __restrict__ X, const u16* __restrict__ BT,
           u16* __restrict__ C, int M, int K, int ntm, int ntn, int ldc)
{
  __shared__ float Af[2][4096];   // 2 x 16 KB: A tile [128][32] fp32, chunk-swizzled
  __shared__ u16   Bs[2][4096];   // 2 x  8 KB: B tile [128][32] bf16, chunk-swizzled
  const int tid  = threadIdx.x;
  const int lane = tid & 63;
  const int wid  = tid >> 6;
  const int l15  = lane & 15;
  const int g    = lane >> 4;
  const int wm   = (wid >> 1) * 64;   // A row base (0/64)
  const int wn   = (wid & 1) * 64;    // B col base (0/64)

  // bijective XCD swizzle + A-strip grouped order
  const int nwg  = gridDim.x;
  const int orig = blockIdx.x;
  const int q8 = nwg >> 3, r8 = nwg & 7;
  const int xcd = orig & 7, loc = orig >> 3;
  const int wg = (xcd < r8 ? xcd * (q8 + 1) : r8 * (q8 + 1) + (xcd - r8) * q8) + loc;
  const int GT  = 8;
  const int gsz = GT * ntn;
  const int tg  = wg / gsz;
  const int rem = wg - tg * gsz;
  const int gt  = (ntm - tg * GT < GT) ? (ntm - tg * GT) : GT;
  const int tn  = rem / gt;
  const int tml = rem - tn * gt;
  const int bm0 = (tg * GT + tml) * 128;
  const int bn0 = tn * 128;

  f32x4 acc[4][4];
  #pragma unroll
  for (int i = 0; i < 4; ++i)
    #pragma unroll
    for (int j = 0; j < 4; ++j) { f32x4 z = {0.f,0.f,0.f,0.f}; acc[i][j] = z; }

  // A staging: chunk c_lin = i*256+tid -> (row = i*32 + (tid>>3), ch = tid&7);
  // source col chunk = ch ^ (row&7) (involution; row&7 == (tid>>3)&7)
  const int srcA = ((tid & 7) ^ ((tid >> 3) & 7)) * 4;   // float index
  u32 aOff[4];
  #pragma unroll
  for (int i = 0; i < 4; ++i) {
    int ar = bm0 + i * 32 + (tid >> 3); if (ar >= M) ar = M - 1;
    aOff[i] = (u32)ar * (u32)K + srcA;
  }
  // B staging: chunk c_lin = j*256+tid -> (row = j*64 + (tid>>2), ch = tid&3);
  // source chunk = ch ^ ((row>>1)&3) = ch ^ ((tid>>3)&3)
  const int srcB = ((tid & 3) ^ ((tid >> 3) & 3)) * 8;   // u16 index
  u32 bOff[2];
  #pragma unroll
  for (int j = 0; j < 2; ++j)
    bOff[j] = (u32)(bn0 + j * 64 + (tid >> 2)) * (u32)K + srcB;

#define STG(BUF, T) do { \
    _Pragma("unroll") for (int i = 0; i < 4; ++i) \
      GLDS16(X + aOff[i] + (T) * 32, &Af[BUF][(i * 256 + tid) * 4]); \
    _Pragma("unroll") for (int j = 0; j < 2; ++j) \
      GLDS16(BT + bOff[j] + (T) * 32, &Bs[BUF][(j * 256 + tid) * 8]); \
  } while (0)

  // frag-read swizzles
  const int cab  = (g ^ ((l15 >> 1) & 3)) * 8;             // B chunk (u16 idx)
  const int ca0A = ((2 * g) ^ (l15 & 7)) * 4;              // A chunk 0 (float idx)
  const int ca1A = ((2 * g + 1) ^ (l15 & 7)) * 4;          // A chunk 1

#define AFRAG(DST, BUF, MI) do { \
    const float* ap = &Af[BUF][(wm + (MI) * 16 + l15) * 32]; \
    f32x4 x0 = *(const f32x4*)&ap[ca0A]; \
    f32x4 x1 = *(const f32x4*)&ap[ca1A]; \
    union { u32 w[4]; bf16x8 v; } uu; \
    uu.w[0] = cvtpk(x0[0], x0[1]); uu.w[1] = cvtpk(x0[2], x0[3]); \
    uu.w[2] = cvtpk(x1[0], x1[1]); uu.w[3] = cvtpk(x1[2], x1[3]); \
    DST = uu.v; \
  } while (0)

  // prologue: stage tile 0, drain
  STG(0, 0);
  asm volatile("s_waitcnt vmcnt(0)" ::: "memory");
  __builtin_amdgcn_s_barrier();

  const int nt = K >> 5;
  for (int t = 0; t < nt; ++t) {
    const int tb = t & 1;
    const bool more = (t + 1 < nt);
    bf16x8 bfr[4], af[2];
    // ---- P0: B frags + A frags (mi 0,1); stage tile t+1 ----
    #pragma unroll
    for (int ni = 0; ni < 4; ++ni)
      bfr[ni] = *(const bf16x8*)&Bs[tb][(wn + ni * 16 + l15) * 32 + cab];
    AFRAG(af[0], tb, 0);
    AFRAG(af[1], tb, 1);
    if (more) STG(tb ^ 1, t + 1);
    __builtin_amdgcn_s_barrier();
    __builtin_amdgcn_s_setprio(1);
    #pragma unroll
    for (int mi = 0; mi < 2; ++mi)
      #pragma unroll
      for (int ni = 0; ni < 4; ++ni)
        acc[mi][ni] = __builtin_amdgcn_mfma_f32_16x16x32_bf16(af[mi], bfr[ni], acc[mi][ni], 0, 0, 0);
    __builtin_amdgcn_s_setprio(0);
    __builtin_amdgcn_s_barrier();
    // ---- P1: A frags (mi 2,3); end-of-tile wait ----
    AFRAG(af[0], tb, 2);
    AFRAG(af[1], tb, 3);
    __builtin_amdgcn_s_barrier();
    __builtin_amdgcn_s_setprio(1);
    #pragma unroll
    for (int mi = 0; mi < 2; ++mi)
      #pragma unroll
      for (int ni = 0; ni < 4; ++ni)
        acc[2 + mi][ni] = __builtin_amdgcn_mfma_f32_16x16x32_bf16(af[mi], bfr[ni], acc[2 + mi][ni], 0, 0, 0);
    __builtin_amdgcn_s_setprio(0);
    if (more) asm volatile("s_waitcnt vmcnt(0)" ::: "memory");
    __builtin_amdgcn_s_barrier();
  }
#undef STG
#undef AFRAG

  // ---- epilogue ----
  #pragma unroll
  for (int mi = 0; mi < 4; ++mi) {
    #pragma unroll
    for (int r = 0; r < 4; ++r) {
      int grow = bm0 + wm + mi * 16 + g * 4 + r;
      if (grow >= M) continue;
      #pragma unroll
      for (int ni = 0; ni < 4; ++ni) {
        int gcol = bn0 + wn + ni * 16 + l15;
        C[(size_t)grow * ldc + gcol] = f2b(acc[mi][ni][r]);
      }
    }
  }
}

// ---------------- gemmk (r9-verified): 256x128 tile, BK=32, 3 LDS buffers ----------------
template<bool OUT_F32>
__global__ __launch_bounds__(512, 4)
void gemmk(const u16* __restrict__ A, const u16* __restrict__ BT,
           void* __restrict__ Cp, const float* __restrict__ bias,
           int M, int K, int ntm, int ntn, int ldc)
{
  __shared__ u16 lds[36864];   // 3 x (8192 A + 4096 B) u16
  const int tid  = threadIdx.x;
  const int lane = tid & 63;
  const int wid  = tid >> 6;
  const int l15  = lane & 15;
  const int g    = lane >> 4;
  const int wm   = (wid >> 1) * 64;   // A row base (0..192)
  const int wn   = (wid & 1) * 64;    // B col base (0/64)

  const int nwg  = gridDim.x;
  const int orig = blockIdx.x;
  const int q8 = nwg >> 3, r8 = nwg & 7;
  const int xcd = orig & 7, loc = orig >> 3;
  const int wg = (xcd < r8 ? xcd * (q8 + 1) : r8 * (q8 + 1) + (xcd - r8) * q8) + loc;
  const int GT  = 4;
  const int gsz = GT * ntn;
  const int tg  = wg / gsz;
  const int rem = wg - tg * gsz;
  const int gt  = (ntm - tg * GT < GT) ? (ntm - tg * GT) : GT;
  const int tn  = rem / gt;
  const int tml = rem - tn * gt;
  const int bm0 = (tg * GT + tml) * 256;
  const int bn0 = tn * 128;

  f32x4 acc[4][4];
  #pragma unroll
  for (int i = 0; i < 4; ++i)
    #pragma unroll
    for (int j = 0; j < 4; ++j) { f32x4 z = {0.f,0.f,0.f,0.f}; acc[i][j] = z; }

  const int rr   = tid >> 2;
  const int ch   = tid & 3;
  const int srcq = (ch ^ ((rr >> 1) & 3)) * 8;
  int ar0 = bm0 + rr;        if (ar0 >= M) ar0 = M - 1;
  int ar1 = bm0 + 128 + rr;  if (ar1 >= M) ar1 = M - 1;
  const u32 aOff0 = (u32)ar0 * (u32)K + srcq;
  const u32 aOff1 = (u32)ar1 * (u32)K + srcq;
  const u32 bOff  = (u32)(bn0 + rr) * (u32)K + srcq;
  const int ld8   = tid * 8;

#define STG(BUF, KO) do { \
    GLDS16(A + aOff0 + (KO), &lds[(BUF) * 12288 + ld8]); \
    GLDS16(A + aOff1 + (KO), &lds[(BUF) * 12288 + 4096 + ld8]); \
    GLDS16(BT + bOff + (KO), &lds[(BUF) * 12288 + 8192 + ld8]); \
  } while (0)

  const int ca = (g ^ ((l15 >> 1) & 3)) * 8;

  STG(0, 0);
  STG(1, 32);
  asm volatile("s_waitcnt vmcnt(3)" ::: "memory");
  __builtin_amdgcn_s_barrier();

  const int nt = K >> 5;
  int bufc = 0, bufn = 2;
  for (int t = 0; t < nt; ++t) {
    const int base = bufc * 12288;
    const bool more = (t + 2 < nt);
    bf16x8 bfr[4], af[2];
    #pragma unroll
    for (int ni = 0; ni < 4; ++ni)
      bfr[ni] = *(const bf16x8*)&lds[base + 8192 + (wn + ni * 16 + l15) * 32 + ca];
    af[0] = *(const bf16x8*)&lds[base + (wm + l15) * 32 + ca];
    af[1] = *(const bf16x8*)&lds[base + (wm + 16 + l15) * 32 + ca];
    if (more) STG(bufn, (t + 2) * 32);
    __builtin_amdgcn_s_barrier();
    __builtin_amdgcn_s_setprio(1);
    #pragma unroll
    for (int mi = 0; mi < 2; ++mi)
      #pragma unroll
      for (int ni = 0; ni < 4; ++ni)
        acc[mi][ni] = __builtin_amdgcn_mfma_f32_16x16x32_bf16(af[mi], bfr[ni], acc[mi][ni], 0, 0, 0);
    __builtin_amdgcn_s_setprio(0);
    __builtin_amdgcn_s_barrier();
    af[0] = *(const bf16x8*)&lds[base + (wm + 32 + l15) * 32 + ca];
    af[1] = *(const bf16x8*)&lds[base + (wm + 48 + l15) * 32 + ca];
    __builtin_amdgcn_s_barrier();
    __builtin_amdgcn_s_setprio(1);
    #pragma unroll
    for (int mi = 0; mi < 2; ++mi)
      #pragma unroll
      for (int ni = 0; ni < 4; ++ni)
        acc[2 + mi][ni] = __builtin_amdgcn_mfma_f32_16x16x32_bf16(af[mi], bfr[ni], acc[2 + mi][ni], 0, 0, 0);
    __builtin_amdgcn_s_setprio(0);
    if (more) asm volatile("s_waitcnt vmcnt(3)" ::: "memory");
    else      asm volatile("s_waitcnt vmcnt(0)" ::: "memory");
    __builtin_amdgcn_s_barrier();
    bufc = (bufc + 1 == 3) ? 0 : bufc + 1;
    bufn = (bufn + 1 == 3) ? 0 : bufn + 1;
  }
#undef STG

  #pragma unroll
  for (int mi = 0; mi < 4; ++mi) {
    #pragma unroll
    for (int r = 0; r < 4; ++r) {
      int grow = bm0 + wm + mi * 16 + g * 4 + r;
      if (grow >= M) continue;
      #pragma unroll
      for (int ni = 0; ni < 4; ++ni) {
        int gcol  = bn0 + wn + ni * 16 + l15;
        float val = acc[mi][ni][r];
        if (OUT_F32) ((float*)Cp)[(size_t)grow * ldc + gcol] = val + bias[gcol];
        else         ((u16*)Cp)[(size_t)grow * ldc + gcol]   = f2b(val);
      }
    }
  }
}

// ---------------- global-token attention, split into chunks ----------------
__global__ __launch_bounds__(256)
void gsplit(const u16* __restrict__ qkv, float* __restrict__ gbuf)
{
  const int c   = blockIdx.x & 15;
  const int h   = (blockIdx.x >> 4) & 7;
  const int b   = blockIdx.x >> 7;
  const int tid = threadIdx.x;
  const int lane = tid & 63;
  const int wid  = tid >> 6;
  const int t0 = c * GCS;
  const int t1 = (t0 + GCS < T_TOK) ? (t0 + GCS) : T_TOK;
  const int nt = t1 - t0;

  __shared__ float sc[GCS];
  __shared__ float q0s[64];
  __shared__ float wredm[4], wreds[4];
  __shared__ float psum[4][64];

  const size_t base = (size_t)b * T_TOK * 1536;
  if (tid < 32) {
    u32 u = ((const u32*)(qkv + base + h * 64))[tid];
    q0s[2 * tid] = blo(u); q0s[2 * tid + 1] = bhi(u);
  }
  __syncthreads();

  float lmax = -INFINITY;
  for (int tt = tid; tt < nt; tt += 256) {
    const uint4* kp = (const uint4*)(qkv + base + (size_t)(t0 + tt) * 1536 + 512 + h * 64);
    float a = 0.f;
    #pragma unroll
    for (int q8 = 0; q8 < 8; ++q8) {
      uint4 kk = kp[q8];
      a += q0s[q8*8+0]*blo(kk.x) + q0s[q8*8+1]*bhi(kk.x)
         + q0s[q8*8+2]*blo(kk.y) + q0s[q8*8+3]*bhi(kk.y)
         + q0s[q8*8+4]*blo(kk.z) + q0s[q8*8+5]*bhi(kk.z)
         + q0s[q8*8+6]*blo(kk.w) + q0s[q8*8+7]*bhi(kk.w);
    }
    a *= 0.125f;
    sc[tt] = a;
    lmax = fmaxf(lmax, a);
  }
  for (int o = 32; o; o >>= 1) lmax = fmaxf(lmax, __shfl_xor(lmax, o, 64));
  if (lane == 0) wredm[wid] = lmax;
  __syncthreads();
  float bmax = fmaxf(fmaxf(wredm[0], wredm[1]), fmaxf(wredm[2], wredm[3]));
  float lsum = 0.f;
  for (int tt = tid; tt < nt; tt += 256) {
    float e = __expf(sc[tt] - bmax);
    sc[tt] = e;
    lsum += e;
  }
  for (int o = 32; o; o >>= 1) lsum += __shfl_xor(lsum, o, 64);
  if (lane == 0) wreds[wid] = lsum;
  __syncthreads();
  float bsum = wreds[0] + wreds[1] + wreds[2] + wreds[3];

  const int g = tid >> 6;
  const int d = tid & 63;
  float acc = 0.f;
  for (int tt = g; tt < nt; tt += 4)
    acc += sc[tt] * b2f(qkv[base + (size_t)(t0 + tt) * 1536 + 1024 + h * 64 + d]);
  psum[g][d] = acc;
  __syncthreads();

  float* rec = gbuf + ((size_t)(b * 8 + h) * GCH + c) * 66;
  if (tid < 64)
    rec[2 + tid] = psum[0][tid] + psum[1][tid] + psum[2][tid] + psum[3][tid];
  if (tid == 64) { rec[0] = bmax; rec[1] = bsum; }
}

__global__ __launch_bounds__(64)
void gmerge(const float* __restrict__ gbuf, u16* __restrict__ attnb)
{
  const int bh = blockIdx.x;
  const int d  = threadIdx.x;
  const float* recs = gbuf + (size_t)bh * GCH * 66;
  float m = -INFINITY;
  #pragma unroll
  for (int c = 0; c < GCH; ++c) m = fmaxf(m, recs[c * 66]);
  float l = 0.f, o = 0.f;
  #pragma unroll
  for (int c = 0; c < GCH; ++c) {
    float e = __expf(recs[c * 66] - m);
    l += recs[c * 66 + 1] * e;
    o += recs[c * 66 + 2 + d] * e;
  }
  const int b = bh >> 3, h = bh & 7;
  attnb[(size_t)b * T_TOK * 512 + h * 64 + d] = f2b(o / l);
}

// ---------------- block-local attention: MFMA flash, 1 workgroup per (b,h,n) ----------------
__global__ __launch_bounds__(256)
void local_attn_mfma(const u16* __restrict__ qkv, u16* __restrict__ attnb)
{
  const int bid = blockIdx.x;
  const int n = bid & 63;
  const int h = (bid >> 6) & 7;
  const int b = bid >> 9;
  const int tid  = threadIdx.x;
  const int lane = tid & 63;
  const int wid  = tid >> 6;
  const int l15  = lane & 15;
  const int g    = lane >> 4;

  __shared__ u16 K_lds[128 * 72];
  __shared__ u16 V_T[64 * 136];
  __shared__ u16 P_lds[4][32 * 72];
  __shared__ float bb[4][2][32];
  __shared__ float Kg[64], Vg[64];

  const size_t rb = (size_t)b * T_TOK;
  if (tid < 64) {
    Kg[tid] = b2f(qkv[rb * 1536 + 512 + h * 64 + tid]);
    Vg[tid] = b2f(qkv[rb * 1536 + 1024 + h * 64 + tid]);
  }

  const int q0row = 1 + n * 128 + wid * 32;
  bf16x8 qf[2][2];
  #pragma unroll
  for (int qt = 0; qt < 2; ++qt)
    #pragma unroll
    for (int kk = 0; kk < 2; ++kk)
      qf[qt][kk] = *(const bf16x8*)(qkv + (rb + q0row + qt * 16 + l15) * 1536 + h * 64 + kk * 32 + g * 8);

  __syncthreads();

  float sg[2];
  #pragma unroll
  for (int qt = 0; qt < 2; ++qt) {
    float part = 0.f;
    #pragma unroll
    for (int kk = 0; kk < 2; ++kk)
      #pragma unroll
      for (int i = 0; i < 8; ++i)
        part += b2f((u16)qf[qt][kk][i]) * Kg[kk * 32 + g * 8 + i];
    part += __shfl_xor(part, 16, 64);
    part += __shfl_xor(part, 32, 64);
    sg[qt] = part * 0.125f;
  }

  float m[2] = {-INFINITY, -INFINITY};
  float l[2] = {0.f, 0.f};
  f32x4 of[2][4];
  #pragma unroll
  for (int qt = 0; qt < 2; ++qt)
    #pragma unroll
    for (int dt = 0; dt < 4; ++dt) { f32x4 z = {0.f,0.f,0.f,0.f}; of[qt][dt] = z; }

  for (int dblk = 0; dblk < 3; ++dblk) {
    const int blk = n + dblk - 1;
    if (blk < 0 || blk >= NBLK) continue;
    const size_t krow0 = rb + 1 + (size_t)blk * 128;

    __syncthreads();
    #pragma unroll
    for (int it = 0; it < 4; ++it) {
      int c = it * 256 + tid;
      int key = c >> 3, oct = c & 7;
      *(uint4*)&K_lds[key * 72 + oct * 8] =
          *(const uint4*)(qkv + (krow0 + key) * 1536 + 512 + h * 64 + oct * 8);
    }
    #pragma unroll
    for (int it = 0; it < 2; ++it) {
      int c = it * 256 + tid;
      int kp2 = c & 63, oct = c >> 6;
      const u16* s0 = qkv + (krow0 + 2 * kp2) * 1536 + 1024 + h * 64 + oct * 8;
      uint4 va = *(const uint4*)s0;
      uint4 vb4 = *(const uint4*)(s0 + 1536);
      union { uint4 q; u16 hh[8]; } ua, ub;
      ua.q = va; ub.q = vb4;
      #pragma unroll
      for (int i = 0; i < 8; ++i) {
        u32 w = (u32)ua.hh[i] | ((u32)ub.hh[i] << 16);
        *(u32*)&V_T[(oct * 8 + i) * 136 + 2 * kp2] = w;
      }
    }
    __syncthreads();

    f32x4 st[2][8];
    #pragma unroll
    for (int kt = 0; kt < 8; ++kt) {
      bf16x8 kfr[2];
      #pragma unroll
      for (int kk = 0; kk < 2; ++kk)
        kfr[kk] = *(const bf16x8*)&K_lds[(kt * 16 + l15) * 72 + kk * 32 + g * 8];
      #pragma unroll
      for (int qt = 0; qt < 2; ++qt) {
        f32x4 z = {0.f,0.f,0.f,0.f};
        z = __builtin_amdgcn_mfma_f32_16x16x32_bf16(kfr[0], qf[qt][0], z, 0, 0, 0);
        z = __builtin_amdgcn_mfma_f32_16x16x32_bf16(kfr[1], qf[qt][1], z, 0, 0, 0);
        st[qt][kt] = z;
      }
    }
    #pragma unroll
    for (int qt = 0; qt < 2; ++qt) {
      float bm = -INFINITY;
      #pragma unroll
      for (int kt = 0; kt < 8; ++kt)
        #pragma unroll
        for (int r = 0; r < 4; ++r) bm = fmaxf(bm, st[qt][kt][r]);
      bm = fmaxf(bm, __shfl_xor(bm, 16, 64));
      bm = fmaxf(bm, __shfl_xor(bm, 32, 64));
      bm *= 0.125f;
      float mn = fmaxf(m[qt], bm);
      float corr = __expf(m[qt] - mn);
      float bsum = 0.f;
      #pragma unroll
      for (int kt = 0; kt < 8; ++kt)
        #pragma unroll
        for (int r = 0; r < 4; ++r) {
          float p = __expf(__builtin_fmaf(st[qt][kt][r], 0.125f, -mn));
          st[qt][kt][r] = p;
          bsum += p;
        }
      bsum += __shfl_xor(bsum, 16, 64);
      bsum += __shfl_xor(bsum, 32, 64);
      l[qt] = l[qt] * corr + bsum;
      m[qt] = mn;
      if (lane < 16) bb[wid][0][qt * 16 + lane] = corr;
    }
    float rc[2][4];
    #pragma unroll
    for (int qt = 0; qt < 2; ++qt)
      #pragma unroll
      for (int r = 0; r < 4; ++r) rc[qt][r] = bb[wid][0][qt * 16 + g * 4 + r];
    #pragma unroll
    for (int qt = 0; qt < 2; ++qt)
      #pragma unroll
      for (int dt = 0; dt < 4; ++dt)
        #pragma unroll
        for (int r = 0; r < 4; ++r) of[qt][dt][r] *= rc[qt][r];

    u16* P_w = (u16*)P_lds[wid];
    #pragma unroll
    for (int half = 0; half < 2; ++half) {
      #pragma unroll
      for (int qt = 0; qt < 2; ++qt)
        #pragma unroll
        for (int k4 = 0; k4 < 4; ++k4) {
          int kt = half * 4 + k4;
          u16 h0 = f2b(st[qt][kt][0]), h1 = f2b(st[qt][kt][1]);
          u16 h2 = f2b(st[qt][kt][2]), h3 = f2b(st[qt][kt][3]);
          uint2 pk = { (u32)h0 | ((u32)h1 << 16), (u32)h2 | ((u32)h3 << 16) };
          *(uint2*)&P_w[(qt * 16 + l15) * 72 + k4 * 16 + g * 4] = pk;
        }
      #pragma unroll
      for (int ks = 0; ks < 2; ++ks) {
        bf16x8 pa[2];
        #pragma unroll
        for (int qt = 0; qt < 2; ++qt)
          pa[qt] = *(const bf16x8*)&P_w[(qt * 16 + l15) * 72 + ks * 32 + g * 8];
        #pragma unroll
        for (int dt = 0; dt < 4; ++dt) {
          bf16x8 vb = *(const bf16x8*)&V_T[(dt * 16 + l15) * 136 + half * 64 + ks * 32 + g * 8];
          #pragma unroll
          for (int qt = 0; qt < 2; ++qt)
            of[qt][dt] = __builtin_amdgcn_mfma_f32_16x16x32_bf16(pa[qt], vb, of[qt][dt], 0, 0, 0);
        }
      }
    }
  }

  const int nz = (n == 0) + (n == NBLK - 1);
  #pragma unroll
  for (int qt = 0; qt < 2; ++qt) {
    float mf   = fmaxf(m[qt], sg[qt]);
    float corr = __expf(m[qt] - mf);
    float eg   = __expf(sg[qt] - mf);
    float lf   = l[qt] * corr + eg;
    if (nz) lf += (float)(nz * 128) * __expf(-mf);
    float inv = 1.f / lf;
    if (lane < 16) {
      bb[wid][0][qt * 16 + lane] = corr * inv;
      bb[wid][1][qt * 16 + lane] = eg * inv;
    }
  }
  float vgr[4];
  #pragma unroll
  for (int dt = 0; dt < 4; ++dt) vgr[dt] = Vg[dt * 16 + l15];
  #pragma unroll
  for (int qt = 0; qt < 2; ++qt)
    #pragma unroll
    for (int r = 0; r < 4; ++r) {
      float af = bb[wid][0][qt * 16 + g * 4 + r];
      float bf = bb[wid][1][qt * 16 + g * 4 + r];
      int row = q0row + qt * 16 + g * 4 + r;
      u16* dst = attnb + (rb + row) * 512 + h * 64;
      #pragma unroll
      for (int dt = 0; dt < 4; ++dt)
        dst[dt * 16 + l15] = f2b(of[qt][dt][r] * af + bf * vgr[dt]);
    }
}

extern "C" void kernel_launch(void* const* d_in, const int* in_sizes, int n_in,
                              void* d_out, int out_size, void* d_ws, size_t ws_size,
                              hipStream_t stream) {
  (void)in_sizes; (void)n_in; (void)out_size; (void)ws_size;
  const float* x  = (const float*)d_in[0];
  const float* Wq = (const float*)d_in[1];
  const float* Wk = (const float*)d_in[2];
  const float* Wv = (const float*)d_in[3];
  const float* Wo = (const float*)d_in[4];
  const float* bo = (const float*)d_in[5];
  float* out = (float*)d_out;

  char* ws = (char*)d_ws;
  u16* qkv   = (u16*)ws;                                 // [16386][1536] bf16
  u16* attnb = (u16*)(ws + 50337792);                    // [16386][512] bf16
  u16* WoT   = (u16*)(ws + 67117056);                    // [1024][512] bf16
  u16* WqkvT = (u16*)d_out;                              // scratch; dead before gemm2
  float* gbuf = (float*)((char*)d_out + (4 << 20));      // 33 KB partials

  dim3 blk(256);
  transposeW<<<dim3(24, 16), blk, 0, stream>>>(Wq, Wk, Wv, 512, WqkvT, 1024);
  gemmf<<<dim3(129 * 12), blk, 0, stream>>>(x, WqkvT, qkv, MROWS, 1024, 129, 12, 1536);
  transposeW<<<dim3(16, 8), blk, 0, stream>>>(Wo, Wo, Wo, 1024, WoT, 512);
  gsplit<<<dim3(256), blk, 0, stream>>>(qkv, gbuf);
  gmerge<<<dim3(16), dim3(64), 0, stream>>>(gbuf, attnb);
  local_attn_mfma<<<dim3(1024), blk, 0, stream>>>(qkv, attnb);
  gemmk<true><<<dim3(65 * 8), dim3(512), 0, stream>>>(attnb, WoT, out, bo, MROWS, 512, 65, 8, 1024);
}

// Round 15
// 203.033 us; speedup vs baseline: 1.0879x; 1.0879x over previous
//
#include <hip/hip_runtime.h>
#include <hip/hip_bf16.h>

#define T_TOK 8193
#define MROWS 16386        // B*T
#define NBLK  64
#define GCH   16           // global-attn chunks per (b,h)
#define GCS   513          // chunk size (16*513 >= 8193)

typedef __attribute__((ext_vector_type(8))) short bf16x8;
typedef __attribute__((ext_vector_type(4))) float f32x4;
typedef unsigned short u16;
typedef unsigned int   u32;

__device__ __forceinline__ float blo(u32 u){ return __uint_as_float(u << 16); }
__device__ __forceinline__ float bhi(u32 u){ return __uint_as_float(u & 0xffff0000u); }
__device__ __forceinline__ u16 f2b(float f){
  u32 u = __float_as_uint(f);
  u = (u + 0x7fffu + ((u >> 16) & 1u)) >> 16;
  return (u16)u;
}
__device__ __forceinline__ float b2f(u16 v){ return __uint_as_float(((u32)v) << 16); }

#define GLDS16(gsrc, ldst) \
  __builtin_amdgcn_global_load_lds((const __attribute__((address_space(1))) void*)(gsrc), \
                                   (__attribute__((address_space(3))) void*)(ldst), 16, 0, 0)

// ---------------- x -> bf16 ----------------
__global__ __launch_bounds__(256)
void convx(const float* __restrict__ x, u16* __restrict__ xb)
{
  const size_t i = (size_t)blockIdx.x * 256 + threadIdx.x;
  const float4* p = (const float4*)x + i * 2;
  float4 a = p[0], b = p[1];
  uint4 st;
  st.x = (u32)f2b(a.x) | ((u32)f2b(a.y) << 16);
  st.y = (u32)f2b(a.z) | ((u32)f2b(a.w) << 16);
  st.z = (u32)f2b(b.x) | ((u32)f2b(b.y) << 16);
  st.w = (u32)f2b(b.z) | ((u32)f2b(b.w) << 16);
  *(uint4*)(xb + i * 8) = st;
}

// ---------------- W [K][N] fp32 (up to 3 parts) -> W^T [N][K] bf16 ----------------
__global__ __launch_bounds__(256)
void transposeW(const float* __restrict__ B0, const float* __restrict__ B1,
                const float* __restrict__ B2, int bpart,
                u16* __restrict__ outT, int K)
{
  __shared__ float tile[64][65];
  const int n0 = blockIdx.x * 64;
  const int k0 = blockIdx.y * 64;
  const int tx = threadIdx.x & 63;
  const int ty = threadIdx.x >> 6;
  const int part = n0 / bpart;
  const float* Bm = part == 0 ? B0 : (part == 1 ? B1 : B2);
  const int bn = n0 - part * bpart;
  #pragma unroll
  for (int i = 0; i < 16; ++i) {
    int k = i * 4 + ty;
    tile[tx][k] = Bm[(size_t)(k0 + k) * bpart + bn + tx];
  }
  __syncthreads();
  #pragma unroll
  for (int i = 0; i < 16; ++i) {
    int r = i * 4 + ty;
    outT[(size_t)(n0 + r) * K + k0 + tx] = f2b(tile[r][tx]);
  }
}

// ---------------- gemmk: 256x128 tile, BK=32, 3 LDS buffers, 2 blocks/CU ----------------
// (r9-verified best: 75.8 us @ gemm1, 0 bank conflicts, MfmaUtil 29%)
// 512 threads = 8 waves (4M x 2N), per-wave 64x64 output (acc 64 VGPR).
// Depth-2 pipeline: stage tile t+2 at P0; counted vmcnt(3) at P1 retires the
// next tile's loads (<=6 outstanding; drain 0 only at the end).
// Chunk swizzle (verified 0-conflict): src chunk c^((r>>1)&3), read g^((l15>>1)&3).
template<bool OUT_F32>
__global__ __launch_bounds__(512, 4)
void gemmk(const u16* __restrict__ A, const u16* __restrict__ BT,
           void* __restrict__ Cp, const float* __restrict__ bias,
           int M, int K, int ntm, int ntn, int ldc)
{
  __shared__ u16 lds[36864];   // 3 x (8192 A + 4096 B) u16
  const int tid  = threadIdx.x;
  const int lane = tid & 63;
  const int wid  = tid >> 6;
  const int l15  = lane & 15;
  const int g    = lane >> 4;
  const int wm   = (wid >> 1) * 64;   // A row base (0..192)
  const int wn   = (wid & 1) * 64;    // B col base (0/64)

  // bijective XCD swizzle + A-strip grouped order
  const int nwg  = gridDim.x;
  const int orig = blockIdx.x;
  const int q8 = nwg >> 3, r8 = nwg & 7;
  const int xcd = orig & 7, loc = orig >> 3;
  const int wg = (xcd < r8 ? xcd * (q8 + 1) : r8 * (q8 + 1) + (xcd - r8) * q8) + loc;
  const int GT  = 4;
  const int gsz = GT * ntn;
  const int tg  = wg / gsz;
  const int rem = wg - tg * gsz;
  const int gt  = (ntm - tg * GT < GT) ? (ntm - tg * GT) : GT;
  const int tn  = rem / gt;
  const int tml = rem - tn * gt;
  const int bm0 = (tg * GT + tml) * 256;
  const int bn0 = tn * 128;

  f32x4 acc[4][4];
  #pragma unroll
  for (int i = 0; i < 4; ++i)
    #pragma unroll
    for (int j = 0; j < 4; ++j) { f32x4 z = {0.f,0.f,0.f,0.f}; acc[i][j] = z; }

  // staging: row rr = tid>>2, chunk ch = tid&3; pre-swizzled source chunk
  const int rr   = tid >> 2;
  const int ch   = tid & 3;
  const int srcq = (ch ^ ((rr >> 1) & 3)) * 8;
  int ar0 = bm0 + rr;        if (ar0 >= M) ar0 = M - 1;
  int ar1 = bm0 + 128 + rr;  if (ar1 >= M) ar1 = M - 1;
  const u32 aOff0 = (u32)ar0 * (u32)K + srcq;
  const u32 aOff1 = (u32)ar1 * (u32)K + srcq;
  const u32 bOff  = (u32)(bn0 + rr) * (u32)K + srcq;
  const int ld8   = tid * 8;

#define STG(BUF, KO) do { \
    GLDS16(A + aOff0 + (KO), &lds[(BUF) * 12288 + ld8]); \
    GLDS16(A + aOff1 + (KO), &lds[(BUF) * 12288 + 4096 + ld8]); \
    GLDS16(BT + bOff + (KO), &lds[(BUF) * 12288 + 8192 + ld8]); \
  } while (0)

  const int ca = (g ^ ((l15 >> 1) & 3)) * 8;

  // prologue: stage tiles 0 and 1; wait tile 0 (retire oldest 3 of 6)
  STG(0, 0);
  STG(1, 32);
  asm volatile("s_waitcnt vmcnt(3)" ::: "memory");
  __builtin_amdgcn_s_barrier();

  const int nt = K >> 5;
  int bufc = 0, bufn = 2;
  for (int t = 0; t < nt; ++t) {
    const int base = bufc * 12288;
    const bool more = (t + 2 < nt);
    bf16x8 bfr[4], af[2];
    // ---- P0: B frags + A frags (mi 0,1), stage tile t+2, 8 MFMA ----
    #pragma unroll
    for (int ni = 0; ni < 4; ++ni)
      bfr[ni] = *(const bf16x8*)&lds[base + 8192 + (wn + ni * 16 + l15) * 32 + ca];
    af[0] = *(const bf16x8*)&lds[base + (wm + l15) * 32 + ca];
    af[1] = *(const bf16x8*)&lds[base + (wm + 16 + l15) * 32 + ca];
    if (more) STG(bufn, (t + 2) * 32);
    __builtin_amdgcn_s_barrier();
    __builtin_amdgcn_s_setprio(1);
    #pragma unroll
    for (int mi = 0; mi < 2; ++mi)
      #pragma unroll
      for (int ni = 0; ni < 4; ++ni)
        acc[mi][ni] = __builtin_amdgcn_mfma_f32_16x16x32_bf16(af[mi], bfr[ni], acc[mi][ni], 0, 0, 0);
    __builtin_amdgcn_s_setprio(0);
    __builtin_amdgcn_s_barrier();
    // ---- P1: A frags (mi 2,3), 8 MFMA, counted vmcnt ----
    af[0] = *(const bf16x8*)&lds[base + (wm + 32 + l15) * 32 + ca];
    af[1] = *(const bf16x8*)&lds[base + (wm + 48 + l15) * 32 + ca];
    __builtin_amdgcn_s_barrier();
    __builtin_amdgcn_s_setprio(1);
    #pragma unroll
    for (int mi = 0; mi < 2; ++mi)
      #pragma unroll
      for (int ni = 0; ni < 4; ++ni)
        acc[2 + mi][ni] = __builtin_amdgcn_mfma_f32_16x16x32_bf16(af[mi], bfr[ni], acc[2 + mi][ni], 0, 0, 0);
    __builtin_amdgcn_s_setprio(0);
    if (more) asm volatile("s_waitcnt vmcnt(3)" ::: "memory");
    else      asm volatile("s_waitcnt vmcnt(0)" ::: "memory");
    __builtin_amdgcn_s_barrier();
    bufc = (bufc + 1 == 3) ? 0 : bufc + 1;
    bufn = (bufn + 1 == 3) ? 0 : bufn + 1;
  }
#undef STG

  // ---- epilogue ----
  #pragma unroll
  for (int mi = 0; mi < 4; ++mi) {
    #pragma unroll
    for (int r = 0; r < 4; ++r) {
      int grow = bm0 + wm + mi * 16 + g * 4 + r;
      if (grow >= M) continue;
      #pragma unroll
      for (int ni = 0; ni < 4; ++ni) {
        int gcol  = bn0 + wn + ni * 16 + l15;
        float val = acc[mi][ni][r];
        if (OUT_F32) ((float*)Cp)[(size_t)grow * ldc + gcol] = val + bias[gcol];
        else         ((u16*)Cp)[(size_t)grow * ldc + gcol]   = f2b(val);
      }
    }
  }
}

// ---------------- global-token attention, split into chunks ----------------
__global__ __launch_bounds__(256)
void gsplit(const u16* __restrict__ qkv, float* __restrict__ gbuf)
{
  const int c   = blockIdx.x & 15;
  const int h   = (blockIdx.x >> 4) & 7;
  const int b   = blockIdx.x >> 7;
  const int tid = threadIdx.x;
  const int lane = tid & 63;
  const int wid  = tid >> 6;
  const int t0 = c * GCS;
  const int t1 = (t0 + GCS < T_TOK) ? (t0 + GCS) : T_TOK;
  const int nt = t1 - t0;

  __shared__ float sc[GCS];
  __shared__ float q0s[64];
  __shared__ float wredm[4], wreds[4];
  __shared__ float psum[4][64];

  const size_t base = (size_t)b * T_TOK * 1536;
  if (tid < 32) {
    u32 u = ((const u32*)(qkv + base + h * 64))[tid];
    q0s[2 * tid] = blo(u); q0s[2 * tid + 1] = bhi(u);
  }
  __syncthreads();

  float lmax = -INFINITY;
  for (int tt = tid; tt < nt; tt += 256) {
    const uint4* kp = (const uint4*)(qkv + base + (size_t)(t0 + tt) * 1536 + 512 + h * 64);
    float a = 0.f;
    #pragma unroll
    for (int q8 = 0; q8 < 8; ++q8) {
      uint4 kk = kp[q8];
      a += q0s[q8*8+0]*blo(kk.x) + q0s[q8*8+1]*bhi(kk.x)
         + q0s[q8*8+2]*blo(kk.y) + q0s[q8*8+3]*bhi(kk.y)
         + q0s[q8*8+4]*blo(kk.z) + q0s[q8*8+5]*bhi(kk.z)
         + q0s[q8*8+6]*blo(kk.w) + q0s[q8*8+7]*bhi(kk.w);
    }
    a *= 0.125f;
    sc[tt] = a;
    lmax = fmaxf(lmax, a);
  }
  for (int o = 32; o; o >>= 1) lmax = fmaxf(lmax, __shfl_xor(lmax, o, 64));
  if (lane == 0) wredm[wid] = lmax;
  __syncthreads();
  float bmax = fmaxf(fmaxf(wredm[0], wredm[1]), fmaxf(wredm[2], wredm[3]));
  float lsum = 0.f;
  for (int tt = tid; tt < nt; tt += 256) {
    float e = __expf(sc[tt] - bmax);
    sc[tt] = e;
    lsum += e;
  }
  for (int o = 32; o; o >>= 1) lsum += __shfl_xor(lsum, o, 64);
  if (lane == 0) wreds[wid] = lsum;
  __syncthreads();
  float bsum = wreds[0] + wreds[1] + wreds[2] + wreds[3];

  const int g = tid >> 6;
  const int d = tid & 63;
  float acc = 0.f;
  for (int tt = g; tt < nt; tt += 4)
    acc += sc[tt] * b2f(qkv[base + (size_t)(t0 + tt) * 1536 + 1024 + h * 64 + d]);
  psum[g][d] = acc;
  __syncthreads();

  float* rec = gbuf + ((size_t)(b * 8 + h) * GCH + c) * 66;
  if (tid < 64)
    rec[2 + tid] = psum[0][tid] + psum[1][tid] + psum[2][tid] + psum[3][tid];
  if (tid == 64) { rec[0] = bmax; rec[1] = bsum; }
}

__global__ __launch_bounds__(64)
void gmerge(const float* __restrict__ gbuf, u16* __restrict__ attnb)
{
  const int bh = blockIdx.x;
  const int d  = threadIdx.x;
  const float* recs = gbuf + (size_t)bh * GCH * 66;
  float m = -INFINITY;
  #pragma unroll
  for (int c = 0; c < GCH; ++c) m = fmaxf(m, recs[c * 66]);
  float l = 0.f, o = 0.f;
  #pragma unroll
  for (int c = 0; c < GCH; ++c) {
    float e = __expf(recs[c * 66] - m);
    l += recs[c * 66 + 1] * e;
    o += recs[c * 66 + 2 + d] * e;
  }
  const int b = bh >> 3, h = bh & 7;
  attnb[(size_t)b * T_TOK * 512 + h * 64 + d] = f2b(o / l);
}

// ---------------- block-local attention: MFMA flash, 1 workgroup per (b,h,n) ----------------
__global__ __launch_bounds__(256)
void local_attn_mfma(const u16* __restrict__ qkv, u16* __restrict__ attnb)
{
  const int bid = blockIdx.x;
  const int n = bid & 63;
  const int h = (bid >> 6) & 7;
  const int b = bid >> 9;
  const int tid  = threadIdx.x;
  const int lane = tid & 63;
  const int wid  = tid >> 6;
  const int l15  = lane & 15;
  const int g    = lane >> 4;

  __shared__ u16 K_lds[128 * 72];
  __shared__ u16 V_T[64 * 136];
  __shared__ u16 P_lds[4][32 * 72];
  __shared__ float bb[4][2][32];
  __shared__ float Kg[64], Vg[64];

  const size_t rb = (size_t)b * T_TOK;
  if (tid < 64) {
    Kg[tid] = b2f(qkv[rb * 1536 + 512 + h * 64 + tid]);
    Vg[tid] = b2f(qkv[rb * 1536 + 1024 + h * 64 + tid]);
  }

  const int q0row = 1 + n * 128 + wid * 32;
  bf16x8 qf[2][2];
  #pragma unroll
  for (int qt = 0; qt < 2; ++qt)
    #pragma unroll
    for (int kk = 0; kk < 2; ++kk)
      qf[qt][kk] = *(const bf16x8*)(qkv + (rb + q0row + qt * 16 + l15) * 1536 + h * 64 + kk * 32 + g * 8);

  __syncthreads();

  float sg[2];
  #pragma unroll
  for (int qt = 0; qt < 2; ++qt) {
    float part = 0.f;
    #pragma unroll
    for (int kk = 0; kk < 2; ++kk)
      #pragma unroll
      for (int i = 0; i < 8; ++i)
        part += b2f((u16)qf[qt][kk][i]) * Kg[kk * 32 + g * 8 + i];
    part += __shfl_xor(part, 16, 64);
    part += __shfl_xor(part, 32, 64);
    sg[qt] = part * 0.125f;
  }

  float m[2] = {-INFINITY, -INFINITY};
  float l[2] = {0.f, 0.f};
  f32x4 of[2][4];
  #pragma unroll
  for (int qt = 0; qt < 2; ++qt)
    #pragma unroll
    for (int dt = 0; dt < 4; ++dt) { f32x4 z = {0.f,0.f,0.f,0.f}; of[qt][dt] = z; }

  for (int dblk = 0; dblk < 3; ++dblk) {
    const int blk = n + dblk - 1;
    if (blk < 0 || blk >= NBLK) continue;
    const size_t krow0 = rb + 1 + (size_t)blk * 128;

    __syncthreads();
    #pragma unroll
    for (int it = 0; it < 4; ++it) {
      int c = it * 256 + tid;
      int key = c >> 3, oct = c & 7;
      *(uint4*)&K_lds[key * 72 + oct * 8] =
          *(const uint4*)(qkv + (krow0 + key) * 1536 + 512 + h * 64 + oct * 8);
    }
    #pragma unroll
    for (int it = 0; it < 2; ++it) {
      int c = it * 256 + tid;
      int kp2 = c & 63, oct = c >> 6;
      const u16* s0 = qkv + (krow0 + 2 * kp2) * 1536 + 1024 + h * 64 + oct * 8;
      uint4 va = *(const uint4*)s0;
      uint4 vb4 = *(const uint4*)(s0 + 1536);
      union { uint4 q; u16 hh[8]; } ua, ub;
      ua.q = va; ub.q = vb4;
      #pragma unroll
      for (int i = 0; i < 8; ++i) {
        u32 w = (u32)ua.hh[i] | ((u32)ub.hh[i] << 16);
        *(u32*)&V_T[(oct * 8 + i) * 136 + 2 * kp2] = w;
      }
    }
    __syncthreads();

    f32x4 st[2][8];
    #pragma unroll
    for (int kt = 0; kt < 8; ++kt) {
      bf16x8 kfr[2];
      #pragma unroll
      for (int kk = 0; kk < 2; ++kk)
        kfr[kk] = *(const bf16x8*)&K_lds[(kt * 16 + l15) * 72 + kk * 32 + g * 8];
      #pragma unroll
      for (int qt = 0; qt < 2; ++qt) {
        f32x4 z = {0.f,0.f,0.f,0.f};
        z = __builtin_amdgcn_mfma_f32_16x16x32_bf16(kfr[0], qf[qt][0], z, 0, 0, 0);
        z = __builtin_amdgcn_mfma_f32_16x16x32_bf16(kfr[1], qf[qt][1], z, 0, 0, 0);
        st[qt][kt] = z;
      }
    }
    #pragma unroll
    for (int qt = 0; qt < 2; ++qt) {
      float bm = -INFINITY;
      #pragma unroll
      for (int kt = 0; kt < 8; ++kt)
        #pragma unroll
        for (int r = 0; r < 4; ++r) bm = fmaxf(bm, st[qt][kt][r]);
      bm = fmaxf(bm, __shfl_xor(bm, 16, 64));
      bm = fmaxf(bm, __shfl_xor(bm, 32, 64));
      bm *= 0.125f;
      float mn = fmaxf(m[qt], bm);
      float corr = __expf(m[qt] - mn);
      float bsum = 0.f;
      #pragma unroll
      for (int kt = 0; kt < 8; ++kt)
        #pragma unroll
        for (int r = 0; r < 4; ++r) {
          float p = __expf(__builtin_fmaf(st[qt][kt][r], 0.125f, -mn));
          st[qt][kt][r] = p;
          bsum += p;
        }
      bsum += __shfl_xor(bsum, 16, 64);
      bsum += __shfl_xor(bsum, 32, 64);
      l[qt] = l[qt] * corr + bsum;
      m[qt] = mn;
      if (lane < 16) bb[wid][0][qt * 16 + lane] = corr;
    }
    float rc[2][4];
    #pragma unroll
    for (int qt = 0; qt < 2; ++qt)
      #pragma unroll
      for (int r = 0; r < 4; ++r) rc[qt][r] = bb[wid][0][qt * 16 + g * 4 + r];
    #pragma unroll
    for (int qt = 0; qt < 2; ++qt)
      #pragma unroll
      for (int dt = 0; dt < 4; ++dt)
        #pragma unroll
        for (int r = 0; r < 4; ++r) of[qt][dt][r] *= rc[qt][r];

    u16* P_w = (u16*)P_lds[wid];
    #pragma unroll
    for (int half = 0; half < 2; ++half) {
      #pragma unroll
      for (int qt = 0; qt < 2; ++qt)
        #pragma unroll
        for (int k4 = 0; k4 < 4; ++k4) {
          int kt = half * 4 + k4;
          u16 h0 = f2b(st[qt][kt][0]), h1 = f2b(st[qt][kt][1]);
          u16 h2 = f2b(st[qt][kt][2]), h3 = f2b(st[qt][kt][3]);
          uint2 pk = { (u32)h0 | ((u32)h1 << 16), (u32)h2 | ((u32)h3 << 16) };
          *(uint2*)&P_w[(qt * 16 + l15) * 72 + k4 * 16 + g * 4] = pk;
        }
      #pragma unroll
      for (int ks = 0; ks < 2; ++ks) {
        bf16x8 pa[2];
        #pragma unroll
        for (int qt = 0; qt < 2; ++qt)
          pa[qt] = *(const bf16x8*)&P_w[(qt * 16 + l15) * 72 + ks * 32 + g * 8];
        #pragma unroll
        for (int dt = 0; dt < 4; ++dt) {
          bf16x8 vb = *(const bf16x8*)&V_T[(dt * 16 + l15) * 136 + half * 64 + ks * 32 + g * 8];
          #pragma unroll
          for (int qt = 0; qt < 2; ++qt)
            of[qt][dt] = __builtin_amdgcn_mfma_f32_16x16x32_bf16(pa[qt], vb, of[qt][dt], 0, 0, 0);
        }
      }
    }
  }

  const int nz = (n == 0) + (n == NBLK - 1);
  #pragma unroll
  for (int qt = 0; qt < 2; ++qt) {
    float mf   = fmaxf(m[qt], sg[qt]);
    float corr = __expf(m[qt] - mf);
    float eg   = __expf(sg[qt] - mf);
    float lf   = l[qt] * corr + eg;
    if (nz) lf += (float)(nz * 128) * __expf(-mf);
    float inv = 1.f / lf;
    if (lane < 16) {
      bb[wid][0][qt * 16 + lane] = corr * inv;
      bb[wid][1][qt * 16 + lane] = eg * inv;
    }
  }
  float vgr[4];
  #pragma unroll
  for (int dt = 0; dt < 4; ++dt) vgr[dt] = Vg[dt * 16 + l15];
  #pragma unroll
  for (int qt = 0; qt < 2; ++qt)
    #pragma unroll
    for (int r = 0; r < 4; ++r) {
      float af = bb[wid][0][qt * 16 + g * 4 + r];
      float bf = bb[wid][1][qt * 16 + g * 4 + r];
      int row = q0row + qt * 16 + g * 4 + r;
      u16* dst = attnb + (rb + row) * 512 + h * 64;
      #pragma unroll
      for (int dt = 0; dt < 4; ++dt)
        dst[dt * 16 + l15] = f2b(of[qt][dt][r] * af + bf * vgr[dt]);
    }
}

extern "C" void kernel_launch(void* const* d_in, const int* in_sizes, int n_in,
                              void* d_out, int out_size, void* d_ws, size_t ws_size,
                              hipStream_t stream) {
  (void)in_sizes; (void)n_in; (void)out_size; (void)ws_size;
  const float* x  = (const float*)d_in[0];
  const float* Wq = (const float*)d_in[1];
  const float* Wk = (const float*)d_in[2];
  const float* Wv = (const float*)d_in[3];
  const float* Wo = (const float*)d_in[4];
  const float* bo = (const float*)d_in[5];
  float* out = (float*)d_out;

  char* ws = (char*)d_ws;
  u16* qkv   = (u16*)ws;                                 // [16386][1536] bf16
  u16* xb    = (u16*)(ws + 50337792);                    // [16386][1024] bf16 (dead after gemm1)
  u16* attnb = (u16*)(ws + 50337792);                    // [16386][512] bf16 (reuses xb)
  u16* WoT   = (u16*)(ws + 67117056);                    // [1024][512] bf16
  u16* WqkvT = (u16*)d_out;                              // scratch; dead before gemm2
  float* gbuf = (float*)((char*)d_out + (4 << 20));      // 33 KB partials

  dim3 blk(256);
  convx<<<dim3(8193), blk, 0, stream>>>(x, xb);
  transposeW<<<dim3(24, 16), blk, 0, stream>>>(Wq, Wk, Wv, 512, WqkvT, 1024);
  gemmk<false><<<dim3(65 * 12), dim3(512), 0, stream>>>(xb, WqkvT, qkv, nullptr, MROWS, 1024, 65, 12, 1536);
  transposeW<<<dim3(16, 8), blk, 0, stream>>>(Wo, Wo, Wo, 1024, WoT, 512);
  gsplit<<<dim3(256), blk, 0, stream>>>(qkv, gbuf);
  gmerge<<<dim3(16), dim3(64), 0, stream>>>(gbuf, attnb);
  local_attn_mfma<<<dim3(1024), blk, 0, stream>>>(qkv, attnb);
  gemmk<true><<<dim3(65 * 8), dim3(512), 0, stream>>>(attnb, WoT, out, bo, MROWS, 512, 65, 8, 1024);
}